// Round 4
// baseline (794.934 us; speedup 1.0000x reference)
//
#include <hip/hip_runtime.h>

#define N_NODES 100000
#define N_EDGES 1600000
#define F_IN    128
#define HID     64
#define N_CLASS 40
#define NEG_SLOPE 0.2f
#define ET (N_EDGES + N_NODES)
#define NBLK ((N_NODES + 255) / 256)   // 391 scan blocks

// ---------------------------------------------------------------------------
// h0 = relu(x @ W1 + b1). Split-K register blocking: lane holds ONE 64-deep
// half of W1[:,lane] at a time (64 VGPRs), 8 row-accumulators stay live.
// Two passes over the 8 rows (K-half 0, then K-half 1) -> no spill.
// 3125 blocks x 4 waves x 8 rows == N exactly (no tail).
// ---------------------------------------------------------------------------
__global__ __launch_bounds__(256) void k_lin1(const float* __restrict__ x,
        const float* __restrict__ W1, const float* __restrict__ b1,
        float* __restrict__ out) {
    int lane = threadIdx.x & 63;
    int wid  = blockIdx.x * 4 + (threadIdx.x >> 6);
    int r0 = wid * 8;
    float acc[8];
    float bias = b1[lane];
    #pragma unroll
    for (int i = 0; i < 8; ++i) acc[i] = bias;
    #pragma unroll
    for (int half = 0; half < 2; ++half) {
        float w[64];
        #pragma unroll
        for (int k = 0; k < 64; ++k) w[k] = W1[(half * 64 + k) * HID + lane];
        #pragma unroll
        for (int i = 0; i < 8; ++i) {
            const float4* xr = (const float4*)(x + (size_t)(r0 + i) * F_IN
                                               + half * 64);
            float a0 = 0.f, a1 = 0.f, a2 = 0.f, a3 = 0.f;
            #pragma unroll
            for (int q = 0; q < 16; ++q) {
                float4 xv = xr[q];
                a0 = fmaf(xv.x, w[4 * q + 0], a0);
                a1 = fmaf(xv.y, w[4 * q + 1], a1);
                a2 = fmaf(xv.z, w[4 * q + 2], a2);
                a3 = fmaf(xv.w, w[4 * q + 3], a3);
            }
            acc[i] += (a0 + a1) + (a2 + a3);
        }
    }
    #pragma unroll
    for (int i = 0; i < 8; ++i)
        out[(size_t)(r0 + i) * HID + lane] = fmaxf(acc[i], 0.f);
}

// ---------------------------------------------------------------------------
// h = hin @ Wc ; as_ = h@att_src ; ad_ = h@att_dst.  (hin already activated.)
// Register-W (64 regs, fits), uniform float4 x loads. No tail.
// ---------------------------------------------------------------------------
__global__ __launch_bounds__(256) void k_gemm_att(const float* __restrict__ hin,
        const float* __restrict__ Wc,
        const float* __restrict__ att_s, const float* __restrict__ att_d,
        float* __restrict__ h, float* __restrict__ as_, float* __restrict__ ad_) {
    int lane = threadIdx.x & 63;
    int wid  = blockIdx.x * 4 + (threadIdx.x >> 6);
    float wcol[HID];
    #pragma unroll
    for (int k = 0; k < HID; ++k) wcol[k] = Wc[k * HID + lane];
    float asv = att_s[lane];
    float adv = att_d[lane];
    int r0 = wid * 8;
    #pragma unroll
    for (int i = 0; i < 8; ++i) {
        int r = r0 + i;
        const float4* xr = (const float4*)(hin + (size_t)r * HID);
        float a0 = 0.f, a1 = 0.f, a2 = 0.f, a3 = 0.f;
        #pragma unroll
        for (int q = 0; q < HID / 4; ++q) {
            float4 xv = xr[q];
            a0 = fmaf(xv.x, wcol[4 * q + 0], a0);
            a1 = fmaf(xv.y, wcol[4 * q + 1], a1);
            a2 = fmaf(xv.z, wcol[4 * q + 2], a2);
            a3 = fmaf(xv.w, wcol[4 * q + 3], a3);
        }
        float acc = (a0 + a1) + (a2 + a3);
        h[(size_t)r * HID + lane] = acc;
        float s1 = acc * asv;
        float s2 = acc * adv;
        #pragma unroll
        for (int off = 32; off > 0; off >>= 1) {
            s1 += __shfl_xor(s1, off, 64);
            s2 += __shfl_xor(s2, off, 64);
        }
        if (lane == 0) { as_[r] = s1; ad_[r] = s2; }
    }
}

// ---------------------------------------------------------------------------
// CSR build: degree histogram -> hierarchical scan -> scatter.
// ---------------------------------------------------------------------------
__global__ __launch_bounds__(256) void k_deg(const int* __restrict__ ei,
        int* __restrict__ deg) {
    int i = blockIdx.x * 256 + threadIdx.x;
    if (i >= ET) return;
    int d = (i < N_EDGES) ? ei[N_EDGES + i] : i - N_EDGES;
    atomicAdd(&deg[d], 1);
}

__global__ __launch_bounds__(256) void k_bsum(const int* __restrict__ deg,
        int* __restrict__ bsum) {
    __shared__ int s[256];
    int t = threadIdx.x, i = blockIdx.x * 256 + t;
    s[t] = (i < N_NODES) ? deg[i] : 0;
    __syncthreads();
    for (int off = 128; off > 0; off >>= 1) {
        if (t < off) s[t] += s[t + off];
        __syncthreads();
    }
    if (t == 0) bsum[blockIdx.x] = s[0];
}

__global__ __launch_bounds__(512) void k_bscan(const int* __restrict__ bsum,
        int* __restrict__ bbase) {
    __shared__ int s[512];
    int t = threadIdx.x;
    int v = (t < NBLK) ? bsum[t] : 0;
    s[t] = v; __syncthreads();
    for (int off = 1; off < 512; off <<= 1) {
        int u = (t >= off) ? s[t - off] : 0;
        __syncthreads();
        s[t] += u;
        __syncthreads();
    }
    if (t < NBLK) bbase[t] = s[t] - v;   // exclusive
}

__global__ __launch_bounds__(256) void k_rowptr(const int* __restrict__ deg,
        const int* __restrict__ bbase, int* __restrict__ rowptr) {
    __shared__ int s[256];
    int t = threadIdx.x, i = blockIdx.x * 256 + t;
    int v = (i < N_NODES) ? deg[i] : 0;
    s[t] = v; __syncthreads();
    for (int off = 1; off < 256; off <<= 1) {
        int u = (t >= off) ? s[t - off] : 0;
        __syncthreads();
        s[t] += u;
        __syncthreads();
    }
    if (i < N_NODES) rowptr[i] = bbase[blockIdx.x] + s[t] - v;
    if (i == 0) rowptr[N_NODES] = ET;
}

__global__ __launch_bounds__(256) void k_scatter(const int* __restrict__ ei,
        int* __restrict__ wp, int* __restrict__ col) {
    int i = blockIdx.x * 256 + threadIdx.x;
    if (i >= ET) return;
    int s, d;
    if (i < N_EDGES) { s = ei[i]; d = ei[N_EDGES + i]; }
    else             { s = d = i - N_EDGES; }
    int pos = atomicAdd(&wp[d], 1);
    col[pos] = s;
}

// ---------------------------------------------------------------------------
// Fused GAT aggregate, float4-slot layout: one wave per dst node; 4 edge
// slots x 16 lanes; lane (slot=lane>>4) holds channels (lane&15)*4..+3.
// Softmax normalization folded in. Epilogue: cross-slot reduce + bias [relu].
// ---------------------------------------------------------------------------
template <bool RELU>
__global__ __launch_bounds__(256) void k_gat_agg(const int* __restrict__ rowptr,
        const int* __restrict__ col, const float* __restrict__ h,
        const float* __restrict__ as_, const float* __restrict__ ad_,
        const float* __restrict__ bias, float* __restrict__ outagg) {
    int lane = threadIdx.x & 63;
    int d = blockIdx.x * 4 + (threadIdx.x >> 6);
    if (d >= N_NODES) return;
    int slot = lane >> 4;
    int ch   = (lane & 15) * 4;
    int beg = rowptr[d], end = rowptr[d + 1];
    float add = ad_[d];
    float ax = 0.f, ay = 0.f, az = 0.f, aw = 0.f, den = 0.f;
    for (int c = beg; c < end; c += 64) {
        int n = end - c;
        int sj = 0; float wj = 0.f;
        if (lane < n) {
            sj = col[c + lane];
            float e = as_[sj] + add;
            e = (e > 0.f) ? e : NEG_SLOPE * e;
            wj = __expf(e);
        }
        int m = (n < 64) ? n : 64;
        int iters = (m + 3) >> 2;
        for (int j = 0; j < iters; ++j) {
            int sl = j * 4 + slot;
            int   s = __shfl(sj, sl, 64);
            float w = __shfl(wj, sl, 64);   // 0 for out-of-range slots
            den += w;
            const float4 hv = *(const float4*)(h + (size_t)s * HID + ch);
            ax = fmaf(w, hv.x, ax);
            ay = fmaf(w, hv.y, ay);
            az = fmaf(w, hv.z, az);
            aw = fmaf(w, hv.w, aw);
        }
    }
    #pragma unroll
    for (int off = 16; off <= 32; off <<= 1) {
        ax  += __shfl_xor(ax,  off, 64);
        ay  += __shfl_xor(ay,  off, 64);
        az  += __shfl_xor(az,  off, 64);
        aw  += __shfl_xor(aw,  off, 64);
        den += __shfl_xor(den, off, 64);
    }
    if (slot == 0) {
        float inv = 1.f / (den + 1e-16f);
        const float4 bv = *(const float4*)(bias + ch);
        float4 o;
        o.x = ax * inv + bv.x;
        o.y = ay * inv + bv.y;
        o.z = az * inv + bv.z;
        o.w = aw * inv + bv.w;
        if (RELU) {
            o.x = fmaxf(o.x, 0.f); o.y = fmaxf(o.y, 0.f);
            o.z = fmaxf(o.z, 0.f); o.w = fmaxf(o.w, 0.f);
        }
        *(float4*)(outagg + (size_t)d * HID + ch) = o;
    }
}

// ---------------------------------------------------------------------------
// logits = agg @ W2 + b2 ; out = log_softmax.  (agg already has bias1.)
// ---------------------------------------------------------------------------
__global__ __launch_bounds__(256) void k_final(const float* __restrict__ agg,
        const float* __restrict__ W2, const float* __restrict__ b2,
        float* __restrict__ out) {
    int lane = threadIdx.x & 63;
    int wid  = blockIdx.x * 4 + (threadIdx.x >> 6);
    float wcol[HID];
    #pragma unroll
    for (int k = 0; k < HID; ++k)
        wcol[k] = (lane < N_CLASS) ? W2[k * N_CLASS + lane] : 0.f;
    float bias = (lane < N_CLASS) ? b2[lane] : 0.f;
    int r0 = wid * 8;
    #pragma unroll
    for (int i = 0; i < 8; ++i) {
        int r = r0 + i;
        const float4* xr = (const float4*)(agg + (size_t)r * HID);
        float a0 = bias, a1 = 0.f, a2 = 0.f, a3 = 0.f;
        #pragma unroll
        for (int q = 0; q < HID / 4; ++q) {
            float4 xv = xr[q];
            a0 = fmaf(xv.x, wcol[4 * q + 0], a0);
            a1 = fmaf(xv.y, wcol[4 * q + 1], a1);
            a2 = fmaf(xv.z, wcol[4 * q + 2], a2);
            a3 = fmaf(xv.w, wcol[4 * q + 3], a3);
        }
        float acc = (a0 + a1) + (a2 + a3);
        float mval = (lane < N_CLASS) ? acc : -INFINITY;
        #pragma unroll
        for (int off = 32; off > 0; off >>= 1)
            mval = fmaxf(mval, __shfl_xor(mval, off, 64));
        float ex = (lane < N_CLASS) ? __expf(acc - mval) : 0.f;
        float ssum = ex;
        #pragma unroll
        for (int off = 32; off > 0; off >>= 1)
            ssum += __shfl_xor(ssum, off, 64);
        if (lane < N_CLASS)
            out[(size_t)r * N_CLASS + lane] = acc - mval - logf(ssum);
    }
}

// ---------------------------------------------------------------------------
extern "C" void kernel_launch(void* const* d_in, const int* in_sizes, int n_in,
                              void* d_out, int out_size, void* d_ws, size_t ws_size,
                              hipStream_t stream) {
    const float* x     = (const float*)d_in[0];
    const int*   ei    = (const int*)  d_in[1];
    const float* W1    = (const float*)d_in[2];
    const float* b1    = (const float*)d_in[3];
    const float* Wc0   = (const float*)d_in[4];
    const float* as0   = (const float*)d_in[5];
    const float* ad0   = (const float*)d_in[6];
    const float* bias0 = (const float*)d_in[7];
    const float* Wc1   = (const float*)d_in[8];
    const float* as1   = (const float*)d_in[9];
    const float* ad1   = (const float*)d_in[10];
    const float* bias1 = (const float*)d_in[11];
    const float* W2    = (const float*)d_in[12];
    const float* b2    = (const float*)d_in[13];
    float* out = (float*)d_out;

    // Workspace layout
    float* buf_h  = (float*)d_ws;                      // N*64 f
    float* buf_g  = buf_h + (size_t)N_NODES * HID;     // N*64 f
    float* as_    = buf_g + (size_t)N_NODES * HID;     // N f
    float* ad_    = as_ + N_NODES;                     // N f
    int*   deg    = (int*)(ad_ + N_NODES);             // N i (reused as wp)
    int*   rowptr = deg + N_NODES;                     // N+1 i
    int*   col    = rowptr + (N_NODES + 1);            // ET i
    int*   bsum   = col + ET;                          // NBLK i
    int*   bbase  = bsum + NBLK;                       // NBLK i

    const int ROW_BLOCKS  = 3125;                      // 4 waves x 8 rows = N
    const int EDGE_BLOCKS = (ET + 255) / 256;
    const int AGG_BLOCKS  = (N_NODES + 3) / 4;

    // ---- CSR build (once; reused by both layers) ----
    hipMemsetAsync(deg, 0, N_NODES * sizeof(int), stream);
    k_deg<<<EDGE_BLOCKS, 256, 0, stream>>>(ei, deg);
    k_bsum<<<NBLK, 256, 0, stream>>>(deg, bsum);
    k_bscan<<<1, 512, 0, stream>>>(bsum, bbase);
    k_rowptr<<<NBLK, 256, 0, stream>>>(deg, bbase, rowptr);
    hipMemcpyAsync(deg, rowptr, N_NODES * sizeof(int),
                   hipMemcpyDeviceToDevice, stream);   // deg -> wp
    k_scatter<<<EDGE_BLOCKS, 256, 0, stream>>>(ei, deg, col);

    // h0 = relu(x@W1+b1) -> buf_h
    k_lin1<<<ROW_BLOCKS, 256, 0, stream>>>(x, W1, b1, buf_h);

    // ---- GAT layer 0 ----  (bias0 + relu fused into aggregate epilogue)
    k_gemm_att<<<ROW_BLOCKS, 256, 0, stream>>>(buf_h, Wc0, as0, ad0,
                                               buf_g, as_, ad_);
    k_gat_agg<true><<<AGG_BLOCKS, 256, 0, stream>>>(rowptr, col, buf_g,
                                                    as_, ad_, bias0, buf_h);

    // ---- GAT layer 1 ----  (bias1 fused, no relu)
    k_gemm_att<<<ROW_BLOCKS, 256, 0, stream>>>(buf_h, Wc1, as1, ad1,
                                               buf_g, as_, ad_);
    k_gat_agg<false><<<AGG_BLOCKS, 256, 0, stream>>>(rowptr, col, buf_g,
                                                     as_, ad_, bias1, buf_h);

    // logits + log_softmax
    k_final<<<ROW_BLOCKS, 256, 0, stream>>>(buf_h, W2, b2, out);
}

// Round 5
// 570.027 us; speedup vs baseline: 1.3946x; 1.3946x over previous
//
#include <hip/hip_runtime.h>

#define N_NODES 100000
#define N_EDGES 1600000
#define F_IN    128
#define HID     64
#define N_CLASS 40
#define NEG_SLOPE 0.2f
#define ET (N_EDGES + N_NODES)
#define NBLK ((N_NODES + 255) / 256)   // 391 scan blocks
#define ROW_BLOCKS ((N_NODES + 63) / 64)  // 1563 row-tile blocks

// ---------------------------------------------------------------------------
// Row-GEMM structure (all three dense kernels): lane = row.
//  - 64-row x-tile staged into LDS by lane-parallel coalesced float4 loads.
//  - Each lane owns one output row: acc[OUT] in VGPRs.
//  - Inner loop: 1 ds_read_b128 (pitch 68 -> bank-group (17L+k)%32, conflict-
//    free) + OUT FMAs per k, with W[k][c] a wave-uniform operand -> LLVM
//    promotes to s_load (SGPR operand of v_fma; zero VMEM/LDS/shuffle cost).
//  - Row-major stores via LDS transpose -> coalesced float4.
// ---------------------------------------------------------------------------

// h0 = relu(x @ W1 + b1).  K=128 staged in two 64-col halves (17.4 KB LDS).
__global__ __launch_bounds__(64) void k_lin1(const float* __restrict__ x,
        const float* __restrict__ W1, const float* __restrict__ b1,
        float* __restrict__ out) {
    __shared__ float xs[64 * 68];
    int lane = threadIdx.x;
    int base = blockIdx.x * 64;
    int rem = N_NODES - base; if (rem > 64) rem = 64;

    float acc[64];
    #pragma unroll
    for (int c = 0; c < 64; ++c) acc[c] = b1[c];

    for (int half = 0; half < 2; ++half) {
        __syncthreads();
        #pragma unroll
        for (int j = 0; j < 16; ++j) {
            int idx = j * 64 + lane;          // float4 index in 64x64 tile
            int r   = idx >> 4;
            int c4  = idx & 15;
            int gr  = base + r; if (gr >= N_NODES) gr = N_NODES - 1;
            float4 v = *(const float4*)(x + (size_t)gr * F_IN + half * 64 + c4 * 4);
            *(float4*)(xs + r * 68 + c4 * 4) = v;
        }
        __syncthreads();
        const float* xrow = xs + lane * 68;
        #pragma unroll 2
        for (int k4 = 0; k4 < 16; ++k4) {
            float4 xv = *(const float4*)(xrow + 4 * k4);
            int kb = (half * 64 + 4 * k4) * HID;
            #pragma unroll
            for (int c = 0; c < 64; ++c) {
                acc[c] = fmaf(xv.x, W1[kb + c],           acc[c]);
                acc[c] = fmaf(xv.y, W1[kb + HID + c],     acc[c]);
                acc[c] = fmaf(xv.z, W1[kb + 2 * HID + c], acc[c]);
                acc[c] = fmaf(xv.w, W1[kb + 3 * HID + c], acc[c]);
            }
        }
    }
    // relu + transpose-store
    __syncthreads();
    #pragma unroll
    for (int c4 = 0; c4 < 16; ++c4) {
        float4 o;
        o.x = fmaxf(acc[4 * c4 + 0], 0.f);
        o.y = fmaxf(acc[4 * c4 + 1], 0.f);
        o.z = fmaxf(acc[4 * c4 + 2], 0.f);
        o.w = fmaxf(acc[4 * c4 + 3], 0.f);
        *(float4*)(xs + lane * 68 + c4 * 4) = o;
    }
    __syncthreads();
    #pragma unroll
    for (int j = 0; j < 16; ++j) {
        int idx = j * 64 + lane;
        if (idx < rem * 16) {
            int r = idx >> 4, c4 = idx & 15;
            float4 v = *(const float4*)(xs + r * 68 + c4 * 4);
            *(float4*)(out + (size_t)(base + r) * HID + c4 * 4) = v;
        }
    }
}

// h = hin @ Wc ; as_ = h@att_src ; ad_ = h@att_dst.  (hin already activated.)
// Attention dots are per-lane scalar FMAs over acc[] -- no shuffle reduce.
__global__ __launch_bounds__(64) void k_gemm_att(const float* __restrict__ hin,
        const float* __restrict__ Wc,
        const float* __restrict__ att_s, const float* __restrict__ att_d,
        float* __restrict__ h, float* __restrict__ as_, float* __restrict__ ad_) {
    __shared__ float xs[64 * 68];
    int lane = threadIdx.x;
    int base = blockIdx.x * 64;
    int rem = N_NODES - base; if (rem > 64) rem = 64;

    #pragma unroll
    for (int j = 0; j < 16; ++j) {
        int idx = j * 64 + lane;
        int r   = idx >> 4;
        int c4  = idx & 15;
        int gr  = base + r; if (gr >= N_NODES) gr = N_NODES - 1;
        float4 v = *(const float4*)(hin + (size_t)gr * HID + c4 * 4);
        *(float4*)(xs + r * 68 + c4 * 4) = v;
    }
    __syncthreads();

    float acc[64];
    #pragma unroll
    for (int c = 0; c < 64; ++c) acc[c] = 0.f;
    const float* xrow = xs + lane * 68;
    #pragma unroll 2
    for (int k4 = 0; k4 < 16; ++k4) {
        float4 xv = *(const float4*)(xrow + 4 * k4);
        int kb = 4 * k4 * HID;
        #pragma unroll
        for (int c = 0; c < 64; ++c) {
            acc[c] = fmaf(xv.x, Wc[kb + c],           acc[c]);
            acc[c] = fmaf(xv.y, Wc[kb + HID + c],     acc[c]);
            acc[c] = fmaf(xv.z, Wc[kb + 2 * HID + c], acc[c]);
            acc[c] = fmaf(xv.w, Wc[kb + 3 * HID + c], acc[c]);
        }
    }
    float s1 = 0.f, s2 = 0.f;
    #pragma unroll
    for (int c = 0; c < 64; ++c) {
        s1 = fmaf(acc[c], att_s[c], s1);
        s2 = fmaf(acc[c], att_d[c], s2);
    }
    if (lane < rem) { as_[base + lane] = s1; ad_[base + lane] = s2; }

    __syncthreads();
    #pragma unroll
    for (int c4 = 0; c4 < 16; ++c4) {
        float4 o;
        o.x = acc[4 * c4 + 0]; o.y = acc[4 * c4 + 1];
        o.z = acc[4 * c4 + 2]; o.w = acc[4 * c4 + 3];
        *(float4*)(xs + lane * 68 + c4 * 4) = o;
    }
    __syncthreads();
    #pragma unroll
    for (int j = 0; j < 16; ++j) {
        int idx = j * 64 + lane;
        if (idx < rem * 16) {
            int r = idx >> 4, c4 = idx & 15;
            float4 v = *(const float4*)(xs + r * 68 + c4 * 4);
            *(float4*)(h + (size_t)(base + r) * HID + c4 * 4) = v;
        }
    }
}

// ---------------------------------------------------------------------------
// CSR build: degree histogram -> hierarchical scan -> scatter.
// ---------------------------------------------------------------------------
__global__ __launch_bounds__(256) void k_deg(const int* __restrict__ ei,
        int* __restrict__ deg) {
    int i = blockIdx.x * 256 + threadIdx.x;
    if (i >= ET) return;
    int d = (i < N_EDGES) ? ei[N_EDGES + i] : i - N_EDGES;
    atomicAdd(&deg[d], 1);
}

__global__ __launch_bounds__(256) void k_bsum(const int* __restrict__ deg,
        int* __restrict__ bsum) {
    __shared__ int s[256];
    int t = threadIdx.x, i = blockIdx.x * 256 + t;
    s[t] = (i < N_NODES) ? deg[i] : 0;
    __syncthreads();
    for (int off = 128; off > 0; off >>= 1) {
        if (t < off) s[t] += s[t + off];
        __syncthreads();
    }
    if (t == 0) bsum[blockIdx.x] = s[0];
}

__global__ __launch_bounds__(512) void k_bscan(const int* __restrict__ bsum,
        int* __restrict__ bbase) {
    __shared__ int s[512];
    int t = threadIdx.x;
    int v = (t < NBLK) ? bsum[t] : 0;
    s[t] = v; __syncthreads();
    for (int off = 1; off < 512; off <<= 1) {
        int u = (t >= off) ? s[t - off] : 0;
        __syncthreads();
        s[t] += u;
        __syncthreads();
    }
    if (t < NBLK) bbase[t] = s[t] - v;   // exclusive
}

__global__ __launch_bounds__(256) void k_rowptr(const int* __restrict__ deg,
        const int* __restrict__ bbase, int* __restrict__ rowptr,
        int* __restrict__ wp) {
    __shared__ int s[256];
    int t = threadIdx.x, i = blockIdx.x * 256 + t;
    int v = (i < N_NODES) ? deg[i] : 0;
    s[t] = v; __syncthreads();
    for (int off = 1; off < 256; off <<= 1) {
        int u = (t >= off) ? s[t - off] : 0;
        __syncthreads();
        s[t] += u;
        __syncthreads();
    }
    if (i < N_NODES) {
        int rp = bbase[blockIdx.x] + s[t] - v;
        rowptr[i] = rp;
        wp[i] = rp;
    }
    if (i == 0) rowptr[N_NODES] = ET;
}

__global__ __launch_bounds__(256) void k_scatter(const int* __restrict__ ei,
        int* __restrict__ wp, int* __restrict__ col) {
    int i = blockIdx.x * 256 + threadIdx.x;
    if (i >= ET) return;
    int s, d;
    if (i < N_EDGES) { s = ei[i]; d = ei[N_EDGES + i]; }
    else             { s = d = i - N_EDGES; }
    int pos = atomicAdd(&wp[d], 1);
    col[pos] = s;
}

// ---------------------------------------------------------------------------
// Fused GAT aggregate, float4-slot layout: one wave per dst node; 4 edge
// slots x 16 lanes; lane (slot=lane>>4) holds channels (lane&15)*4..+3.
// Softmax normalization folded in. Epilogue: cross-slot reduce + bias [relu].
// ---------------------------------------------------------------------------
template <bool RELU>
__global__ __launch_bounds__(256) void k_gat_agg(const int* __restrict__ rowptr,
        const int* __restrict__ col, const float* __restrict__ h,
        const float* __restrict__ as_, const float* __restrict__ ad_,
        const float* __restrict__ bias, float* __restrict__ outagg) {
    int lane = threadIdx.x & 63;
    int d = blockIdx.x * 4 + (threadIdx.x >> 6);
    if (d >= N_NODES) return;
    int slot = lane >> 4;
    int ch   = (lane & 15) * 4;
    int beg = rowptr[d], end = rowptr[d + 1];
    float add = ad_[d];
    float ax = 0.f, ay = 0.f, az = 0.f, aw = 0.f, den = 0.f;
    for (int c = beg; c < end; c += 64) {
        int n = end - c;
        int sj = 0; float wj = 0.f;
        if (lane < n) {
            sj = col[c + lane];
            float e = as_[sj] + add;
            e = (e > 0.f) ? e : NEG_SLOPE * e;
            wj = __expf(e);
        }
        int m = (n < 64) ? n : 64;
        int iters = (m + 3) >> 2;
        for (int j = 0; j < iters; ++j) {
            int sl = j * 4 + slot;
            int   s = __shfl(sj, sl, 64);
            float w = __shfl(wj, sl, 64);   // 0 for out-of-range slots
            den += w;
            const float4 hv = *(const float4*)(h + (size_t)s * HID + ch);
            ax = fmaf(w, hv.x, ax);
            ay = fmaf(w, hv.y, ay);
            az = fmaf(w, hv.z, az);
            aw = fmaf(w, hv.w, aw);
        }
    }
    #pragma unroll
    for (int off = 16; off <= 32; off <<= 1) {
        ax  += __shfl_xor(ax,  off, 64);
        ay  += __shfl_xor(ay,  off, 64);
        az  += __shfl_xor(az,  off, 64);
        aw  += __shfl_xor(aw,  off, 64);
        den += __shfl_xor(den, off, 64);
    }
    if (slot == 0) {
        float inv = 1.f / (den + 1e-16f);
        const float4 bv = *(const float4*)(bias + ch);
        float4 o;
        o.x = ax * inv + bv.x;
        o.y = ay * inv + bv.y;
        o.z = az * inv + bv.z;
        o.w = aw * inv + bv.w;
        if (RELU) {
            o.x = fmaxf(o.x, 0.f); o.y = fmaxf(o.y, 0.f);
            o.z = fmaxf(o.z, 0.f); o.w = fmaxf(o.w, 0.f);
        }
        *(float4*)(outagg + (size_t)d * HID + ch) = o;
    }
}

// ---------------------------------------------------------------------------
// logits = agg @ W2 + b2 ; out = log_softmax.  (agg already has bias1.)
// lane = row: log_softmax is fully lane-local (no shuffles).
// ---------------------------------------------------------------------------
__global__ __launch_bounds__(64) void k_final(const float* __restrict__ agg,
        const float* __restrict__ W2, const float* __restrict__ b2,
        float* __restrict__ out) {
    __shared__ float xs[64 * 68];
    int lane = threadIdx.x;
    int base = blockIdx.x * 64;
    int rem = N_NODES - base; if (rem > 64) rem = 64;

    #pragma unroll
    for (int j = 0; j < 16; ++j) {
        int idx = j * 64 + lane;
        int r   = idx >> 4;
        int c4  = idx & 15;
        int gr  = base + r; if (gr >= N_NODES) gr = N_NODES - 1;
        float4 v = *(const float4*)(agg + (size_t)gr * HID + c4 * 4);
        *(float4*)(xs + r * 68 + c4 * 4) = v;
    }
    __syncthreads();

    float acc[N_CLASS];
    #pragma unroll
    for (int c = 0; c < N_CLASS; ++c) acc[c] = b2[c];
    const float* xrow = xs + lane * 68;
    #pragma unroll 2
    for (int k4 = 0; k4 < 16; ++k4) {
        float4 xv = *(const float4*)(xrow + 4 * k4);
        int kb = 4 * k4 * N_CLASS;
        #pragma unroll
        for (int c = 0; c < N_CLASS; ++c) {
            acc[c] = fmaf(xv.x, W2[kb + c],               acc[c]);
            acc[c] = fmaf(xv.y, W2[kb + N_CLASS + c],     acc[c]);
            acc[c] = fmaf(xv.z, W2[kb + 2 * N_CLASS + c], acc[c]);
            acc[c] = fmaf(xv.w, W2[kb + 3 * N_CLASS + c], acc[c]);
        }
    }
    // per-lane log_softmax
    float m = acc[0];
    #pragma unroll
    for (int c = 1; c < N_CLASS; ++c) m = fmaxf(m, acc[c]);
    float ssum = 0.f;
    #pragma unroll
    for (int c = 0; c < N_CLASS; ++c) ssum += __expf(acc[c] - m);
    float lse = m + logf(ssum);

    __syncthreads();
    #pragma unroll
    for (int c4 = 0; c4 < 10; ++c4) {
        float4 o;
        o.x = acc[4 * c4 + 0] - lse; o.y = acc[4 * c4 + 1] - lse;
        o.z = acc[4 * c4 + 2] - lse; o.w = acc[4 * c4 + 3] - lse;
        *(float4*)(xs + lane * N_CLASS + c4 * 4) = o;   // pitch 40 (=out layout)
    }
    __syncthreads();
    #pragma unroll
    for (int j = 0; j < 10; ++j) {
        int idx = j * 64 + lane;                         // float4 index
        if (idx < rem * 10) {
            float4 v = *(const float4*)(xs + idx * 4);
            *(float4*)(out + (size_t)base * N_CLASS + idx * 4) = v;
        }
    }
}

// ---------------------------------------------------------------------------
extern "C" void kernel_launch(void* const* d_in, const int* in_sizes, int n_in,
                              void* d_out, int out_size, void* d_ws, size_t ws_size,
                              hipStream_t stream) {
    const float* x     = (const float*)d_in[0];
    const int*   ei    = (const int*)  d_in[1];
    const float* W1    = (const float*)d_in[2];
    const float* b1    = (const float*)d_in[3];
    const float* Wc0   = (const float*)d_in[4];
    const float* as0   = (const float*)d_in[5];
    const float* ad0   = (const float*)d_in[6];
    const float* bias0 = (const float*)d_in[7];
    const float* Wc1   = (const float*)d_in[8];
    const float* as1   = (const float*)d_in[9];
    const float* ad1   = (const float*)d_in[10];
    const float* bias1 = (const float*)d_in[11];
    const float* W2    = (const float*)d_in[12];
    const float* b2    = (const float*)d_in[13];
    float* out = (float*)d_out;

    // Workspace layout
    float* buf_h  = (float*)d_ws;                      // N*64 f
    float* buf_g  = buf_h + (size_t)N_NODES * HID;     // N*64 f
    float* as_    = buf_g + (size_t)N_NODES * HID;     // N f
    float* ad_    = as_ + N_NODES;                     // N f
    int*   deg    = (int*)(ad_ + N_NODES);             // N i (reused as wp)
    int*   rowptr = deg + N_NODES;                     // N+1 i
    int*   col    = rowptr + (N_NODES + 1);            // ET i
    int*   bsum   = col + ET;                          // NBLK i
    int*   bbase  = bsum + NBLK;                       // NBLK i

    const int EDGE_BLOCKS = (ET + 255) / 256;
    const int AGG_BLOCKS  = (N_NODES + 3) / 4;

    // ---- CSR build (once; reused by both layers) ----
    hipMemsetAsync(deg, 0, N_NODES * sizeof(int), stream);
    k_deg<<<EDGE_BLOCKS, 256, 0, stream>>>(ei, deg);
    k_bsum<<<NBLK, 256, 0, stream>>>(deg, bsum);
    k_bscan<<<1, 512, 0, stream>>>(bsum, bbase);
    k_rowptr<<<NBLK, 256, 0, stream>>>(deg, bbase, rowptr, deg);  // deg -> wp
    k_scatter<<<EDGE_BLOCKS, 256, 0, stream>>>(ei, deg, col);

    // h0 = relu(x@W1+b1) -> buf_h
    k_lin1<<<ROW_BLOCKS, 64, 0, stream>>>(x, W1, b1, buf_h);

    // ---- GAT layer 0 ----  (bias0 + relu fused into aggregate epilogue)
    k_gemm_att<<<ROW_BLOCKS, 64, 0, stream>>>(buf_h, Wc0, as0, ad0,
                                              buf_g, as_, ad_);
    k_gat_agg<true><<<AGG_BLOCKS, 256, 0, stream>>>(rowptr, col, buf_g,
                                                    as_, ad_, bias0, buf_h);

    // ---- GAT layer 1 ----  (bias1 fused, no relu)
    k_gemm_att<<<ROW_BLOCKS, 64, 0, stream>>>(buf_h, Wc1, as1, ad1,
                                              buf_g, as_, ad_);
    k_gat_agg<false><<<AGG_BLOCKS, 256, 0, stream>>>(rowptr, col, buf_g,
                                                     as_, ad_, bias1, buf_h);

    // logits + log_softmax
    k_final<<<ROW_BLOCKS, 64, 0, stream>>>(buf_h, W2, b2, out);
}

// Round 6
// 431.580 us; speedup vs baseline: 1.8419x; 1.3208x over previous
//
#include <hip/hip_runtime.h>

#define N_NODES 100000
#define N_EDGES 1600000
#define F_IN    128
#define HID     64
#define N_CLASS 40
#define NEG_SLOPE 0.2f
#define ET (N_EDGES + N_NODES)          // 1,700,000
#define ROW_BLOCKS ((N_NODES + 63) / 64)

// ---- 2-level radix partition geometry ----
#define NCB   7                          // coarse buckets (dst >> 14)
#define CAP1  294912                     // per-coarse capacity (= 144*2048)
#define BPC   144                        // part2 blocks per coarse bucket
#define NFB   782                        // fine buckets (dst >> 7), 128-node ranges
#define CAPF  2624                       // per-fine capacity (mu 2176 + ~10 sigma)
#define NT1   ((ET + 2047) / 2048)       // 831 part1 tiles

// ---------------------------------------------------------------------------
// h0 = relu(x @ W1 + b1).  lane = row; W via wave-uniform (scalar) loads.
// ---------------------------------------------------------------------------
__global__ __launch_bounds__(64) void k_lin1(const float* __restrict__ x,
        const float* __restrict__ W1, const float* __restrict__ b1,
        float* __restrict__ out) {
    __shared__ float xs[64 * 68];
    int lane = threadIdx.x;
    int base = blockIdx.x * 64;
    int rem = N_NODES - base; if (rem > 64) rem = 64;

    float acc[64];
    #pragma unroll
    for (int c = 0; c < 64; ++c) acc[c] = b1[c];

    for (int half = 0; half < 2; ++half) {
        __syncthreads();
        #pragma unroll
        for (int j = 0; j < 16; ++j) {
            int idx = j * 64 + lane;
            int r   = idx >> 4;
            int c4  = idx & 15;
            int gr  = base + r; if (gr >= N_NODES) gr = N_NODES - 1;
            float4 v = *(const float4*)(x + (size_t)gr * F_IN + half * 64 + c4 * 4);
            *(float4*)(xs + r * 68 + c4 * 4) = v;
        }
        __syncthreads();
        const float* xrow = xs + lane * 68;
        #pragma unroll 2
        for (int k4 = 0; k4 < 16; ++k4) {
            float4 xv = *(const float4*)(xrow + 4 * k4);
            int kb = (half * 64 + 4 * k4) * HID;
            #pragma unroll
            for (int c = 0; c < 64; ++c) {
                acc[c] = fmaf(xv.x, W1[kb + c],           acc[c]);
                acc[c] = fmaf(xv.y, W1[kb + HID + c],     acc[c]);
                acc[c] = fmaf(xv.z, W1[kb + 2 * HID + c], acc[c]);
                acc[c] = fmaf(xv.w, W1[kb + 3 * HID + c], acc[c]);
            }
        }
    }
    __syncthreads();
    #pragma unroll
    for (int c4 = 0; c4 < 16; ++c4) {
        float4 o;
        o.x = fmaxf(acc[4 * c4 + 0], 0.f);
        o.y = fmaxf(acc[4 * c4 + 1], 0.f);
        o.z = fmaxf(acc[4 * c4 + 2], 0.f);
        o.w = fmaxf(acc[4 * c4 + 3], 0.f);
        *(float4*)(xs + lane * 68 + c4 * 4) = o;
    }
    __syncthreads();
    #pragma unroll
    for (int j = 0; j < 16; ++j) {
        int idx = j * 64 + lane;
        if (idx < rem * 16) {
            int r = idx >> 4, c4 = idx & 15;
            float4 v = *(const float4*)(xs + r * 68 + c4 * 4);
            *(float4*)(out + (size_t)(base + r) * HID + c4 * 4) = v;
        }
    }
}

// ---------------------------------------------------------------------------
// h = hin @ Wc ; as_ = h@att_src ; ad_ = h@att_dst.
// ---------------------------------------------------------------------------
__global__ __launch_bounds__(64) void k_gemm_att(const float* __restrict__ hin,
        const float* __restrict__ Wc,
        const float* __restrict__ att_s, const float* __restrict__ att_d,
        float* __restrict__ h, float* __restrict__ as_, float* __restrict__ ad_) {
    __shared__ float xs[64 * 68];
    int lane = threadIdx.x;
    int base = blockIdx.x * 64;
    int rem = N_NODES - base; if (rem > 64) rem = 64;

    #pragma unroll
    for (int j = 0; j < 16; ++j) {
        int idx = j * 64 + lane;
        int r   = idx >> 4;
        int c4  = idx & 15;
        int gr  = base + r; if (gr >= N_NODES) gr = N_NODES - 1;
        float4 v = *(const float4*)(hin + (size_t)gr * HID + c4 * 4);
        *(float4*)(xs + r * 68 + c4 * 4) = v;
    }
    __syncthreads();

    float acc[64];
    #pragma unroll
    for (int c = 0; c < 64; ++c) acc[c] = 0.f;
    const float* xrow = xs + lane * 68;
    #pragma unroll 2
    for (int k4 = 0; k4 < 16; ++k4) {
        float4 xv = *(const float4*)(xrow + 4 * k4);
        int kb = 4 * k4 * HID;
        #pragma unroll
        for (int c = 0; c < 64; ++c) {
            acc[c] = fmaf(xv.x, Wc[kb + c],           acc[c]);
            acc[c] = fmaf(xv.y, Wc[kb + HID + c],     acc[c]);
            acc[c] = fmaf(xv.z, Wc[kb + 2 * HID + c], acc[c]);
            acc[c] = fmaf(xv.w, Wc[kb + 3 * HID + c], acc[c]);
        }
    }
    float s1 = 0.f, s2 = 0.f;
    #pragma unroll
    for (int c = 0; c < 64; ++c) {
        s1 = fmaf(acc[c], att_s[c], s1);
        s2 = fmaf(acc[c], att_d[c], s2);
    }
    if (lane < rem) { as_[base + lane] = s1; ad_[base + lane] = s2; }

    __syncthreads();
    #pragma unroll
    for (int c4 = 0; c4 < 16; ++c4) {
        float4 o;
        o.x = acc[4 * c4 + 0]; o.y = acc[4 * c4 + 1];
        o.z = acc[4 * c4 + 2]; o.w = acc[4 * c4 + 3];
        *(float4*)(xs + lane * 68 + c4 * 4) = o;
    }
    __syncthreads();
    #pragma unroll
    for (int j = 0; j < 16; ++j) {
        int idx = j * 64 + lane;
        if (idx < rem * 16) {
            int r = idx >> 4, c4 = idx & 15;
            float4 v = *(const float4*)(xs + r * 68 + c4 * 4);
            *(float4*)(h + (size_t)(base + r) * HID + c4 * 4) = v;
        }
    }
}

// ---------------------------------------------------------------------------
// Partition level 1: edges -> 7 coarse buckets (dst>>14). LDS-staged, all
// global writes are coalesced block-local runs (full-line writebacks).
// ---------------------------------------------------------------------------
__global__ __launch_bounds__(256) void k_part1(const int* __restrict__ ei,
        int* __restrict__ tail1, int2* __restrict__ buf1) {
    __shared__ int2 eb[2048];
    __shared__ int hist[NCB], lbase[NCB], loff[NCB], goff[NCB];
    int t = threadIdx.x;
    int tileBase = blockIdx.x * 2048;
    int total = ET - tileBase; if (total > 2048) total = 2048;
    if (t < NCB) hist[t] = 0;
    __syncthreads();

    int sr[8], dr[8];
    #pragma unroll
    for (int r = 0; r < 8; ++r) {
        int i = tileBase + r * 256 + t;
        int s = -1, d = -1;
        if (i < ET) {
            if (i < N_EDGES) { s = ei[i]; d = ei[N_EDGES + i]; }
            else             { s = d = i - N_EDGES; }
            atomicAdd(&hist[d >> 14], 1);
        }
        sr[r] = s; dr[r] = d;
    }
    __syncthreads();
    if (t == 0) {
        int run = 0;
        for (int b = 0; b < NCB; ++b) { lbase[b] = run; loff[b] = 0; run += hist[b]; }
    }
    __syncthreads();
    if (t < NCB && hist[t] > 0) goff[t] = atomicAdd(&tail1[t], hist[t]);
    #pragma unroll
    for (int r = 0; r < 8; ++r) {
        if (dr[r] >= 0) {
            int b = dr[r] >> 14;
            int p = lbase[b] + atomicAdd(&loff[b], 1);
            eb[p] = make_int2(sr[r], dr[r]);
        }
    }
    __syncthreads();
    for (int j = t; j < total; j += 256) {
        int2 e = eb[j];
        int b = e.y >> 14;
        buf1[(size_t)b * CAP1 + goff[b] + (j - lbase[b])] = e;
    }
}

// ---------------------------------------------------------------------------
// Partition level 2: coarse bucket -> 128 fine buckets (128-dst ranges).
// ---------------------------------------------------------------------------
__global__ __launch_bounds__(256) void k_part2(const int2* __restrict__ buf1,
        const int* __restrict__ tail1, int* __restrict__ fcnt,
        int2* __restrict__ buf2) {
    __shared__ int2 eb[2048];
    __shared__ int hist[128], lbase[128], loff[128], goff[128], sc[128];
    int t = threadIdx.x;
    int cb   = blockIdx.x / BPC;
    int tile = blockIdx.x % BPC;
    int n1 = tail1[cb];
    int base = tile * 2048;
    if (base >= n1) return;
    int total = n1 - base; if (total > 2048) total = 2048;
    if (t < 128) hist[t] = 0;
    __syncthreads();

    int sr[8], dr[8];
    #pragma unroll
    for (int r = 0; r < 8; ++r) {
        int i = base + r * 256 + t;
        int s = -1, d = -1;
        if (i < n1) {
            int2 e = buf1[(size_t)cb * CAP1 + i];
            s = e.x; d = e.y;
            atomicAdd(&hist[(d >> 7) & 127], 1);
        }
        sr[r] = s; dr[r] = d;
    }
    __syncthreads();
    // parallel exclusive scan of hist[128]
    if (t < 128) sc[t] = hist[t];
    __syncthreads();
    for (int off = 1; off < 128; off <<= 1) {
        int u = (t < 128 && t >= off) ? sc[t - off] : 0;
        __syncthreads();
        if (t < 128) sc[t] += u;
        __syncthreads();
    }
    if (t < 128) { lbase[t] = sc[t] - hist[t]; loff[t] = 0; }
    __syncthreads();
    if (t < 128 && hist[t] > 0)
        goff[t] = atomicAdd(&fcnt[cb * 128 + t], hist[t]);
    #pragma unroll
    for (int r = 0; r < 8; ++r) {
        if (dr[r] >= 0) {
            int f = (dr[r] >> 7) & 127;
            int p = lbase[f] + atomicAdd(&loff[f], 1);
            eb[p] = make_int2(sr[r], dr[r]);
        }
    }
    __syncthreads();
    for (int j = t; j < total; j += 256) {
        int2 e = eb[j];
        int f = (e.y >> 7) & 127;
        buf2[(size_t)(e.y >> 7) * CAPF + goff[f] + (j - lbase[f])] = e;
    }
}

// ---------------------------------------------------------------------------
// Scan of fine-bucket counts -> global bases; also rowptr[N] = ET.
// ---------------------------------------------------------------------------
__global__ __launch_bounds__(1024) void k_fscan(const int* __restrict__ fcnt,
        int* __restrict__ fbase, int* __restrict__ rowptr) {
    __shared__ int s[1024];
    int t = threadIdx.x;
    int v = (t < NFB) ? fcnt[t] : 0;
    s[t] = v;
    __syncthreads();
    for (int off = 1; off < 1024; off <<= 1) {
        int u = (t >= off) ? s[t - off] : 0;
        __syncthreads();
        s[t] += u;
        __syncthreads();
    }
    if (t < NFB) fbase[t] = s[t] - v;   // exclusive
    if (t == 0) rowptr[N_NODES] = ET;
}

// ---------------------------------------------------------------------------
// Partition level 3: fine bucket -> exact per-node CSR. One block per fine
// bucket; LDS reorder; col segment + rowptr slice written fully coalesced.
// ---------------------------------------------------------------------------
__global__ __launch_bounds__(256) void k_part3(const int2* __restrict__ buf2,
        const int* __restrict__ fcnt, const int* __restrict__ fbase,
        int* __restrict__ rowptr, int* __restrict__ col) {
    __shared__ int2 eb[CAPF];
    __shared__ int cs[CAPF];
    __shared__ int hist[128], lbase[128], loff[128], sc[128];
    int t = threadIdx.x;
    int fb = blockIdx.x;
    int nF = fcnt[fb];
    int gb = fbase[fb];
    int dbase = fb * 128;
    if (t < 128) hist[t] = 0;
    __syncthreads();
    for (int j = t; j < nF; j += 256) {
        int2 e = buf2[(size_t)fb * CAPF + j];
        eb[j] = e;
        atomicAdd(&hist[e.y - dbase], 1);
    }
    __syncthreads();
    if (t < 128) sc[t] = hist[t];
    __syncthreads();
    for (int off = 1; off < 128; off <<= 1) {
        int u = (t < 128 && t >= off) ? sc[t - off] : 0;
        __syncthreads();
        if (t < 128) sc[t] += u;
        __syncthreads();
    }
    if (t < 128) { lbase[t] = sc[t] - hist[t]; loff[t] = 0; }
    __syncthreads();
    if (t < 128 && dbase + t < N_NODES) rowptr[dbase + t] = gb + lbase[t];
    for (int j = t; j < nF; j += 256) {
        int2 e = eb[j];
        int r = e.y - dbase;
        int p = lbase[r] + atomicAdd(&loff[r], 1);
        cs[p] = e.x;
    }
    __syncthreads();
    for (int j = t; j < nF; j += 256) col[gb + j] = cs[j];
}

// ---------------------------------------------------------------------------
// Fused GAT aggregate (unchanged): one wave per dst node; float4-slot layout.
// ---------------------------------------------------------------------------
template <bool RELU>
__global__ __launch_bounds__(256) void k_gat_agg(const int* __restrict__ rowptr,
        const int* __restrict__ col, const float* __restrict__ h,
        const float* __restrict__ as_, const float* __restrict__ ad_,
        const float* __restrict__ bias, float* __restrict__ outagg) {
    int lane = threadIdx.x & 63;
    int d = blockIdx.x * 4 + (threadIdx.x >> 6);
    if (d >= N_NODES) return;
    int slot = lane >> 4;
    int ch   = (lane & 15) * 4;
    int beg = rowptr[d], end = rowptr[d + 1];
    float add = ad_[d];
    float ax = 0.f, ay = 0.f, az = 0.f, aw = 0.f, den = 0.f;
    for (int c = beg; c < end; c += 64) {
        int n = end - c;
        int sj = 0; float wj = 0.f;
        if (lane < n) {
            sj = col[c + lane];
            float e = as_[sj] + add;
            e = (e > 0.f) ? e : NEG_SLOPE * e;
            wj = __expf(e);
        }
        int m = (n < 64) ? n : 64;
        int iters = (m + 3) >> 2;
        for (int j = 0; j < iters; ++j) {
            int sl = j * 4 + slot;
            int   s = __shfl(sj, sl, 64);
            float w = __shfl(wj, sl, 64);
            den += w;
            const float4 hv = *(const float4*)(h + (size_t)s * HID + ch);
            ax = fmaf(w, hv.x, ax);
            ay = fmaf(w, hv.y, ay);
            az = fmaf(w, hv.z, az);
            aw = fmaf(w, hv.w, aw);
        }
    }
    #pragma unroll
    for (int off = 16; off <= 32; off <<= 1) {
        ax  += __shfl_xor(ax,  off, 64);
        ay  += __shfl_xor(ay,  off, 64);
        az  += __shfl_xor(az,  off, 64);
        aw  += __shfl_xor(aw,  off, 64);
        den += __shfl_xor(den, off, 64);
    }
    if (slot == 0) {
        float inv = 1.f / (den + 1e-16f);
        const float4 bv = *(const float4*)(bias + ch);
        float4 o;
        o.x = ax * inv + bv.x;
        o.y = ay * inv + bv.y;
        o.z = az * inv + bv.z;
        o.w = aw * inv + bv.w;
        if (RELU) {
            o.x = fmaxf(o.x, 0.f); o.y = fmaxf(o.y, 0.f);
            o.z = fmaxf(o.z, 0.f); o.w = fmaxf(o.w, 0.f);
        }
        *(float4*)(outagg + (size_t)d * HID + ch) = o;
    }
}

// ---------------------------------------------------------------------------
// logits = agg @ W2 + b2 ; out = log_softmax. lane = row.
// ---------------------------------------------------------------------------
__global__ __launch_bounds__(64) void k_final(const float* __restrict__ agg,
        const float* __restrict__ W2, const float* __restrict__ b2,
        float* __restrict__ out) {
    __shared__ float xs[64 * 68];
    int lane = threadIdx.x;
    int base = blockIdx.x * 64;
    int rem = N_NODES - base; if (rem > 64) rem = 64;

    #pragma unroll
    for (int j = 0; j < 16; ++j) {
        int idx = j * 64 + lane;
        int r   = idx >> 4;
        int c4  = idx & 15;
        int gr  = base + r; if (gr >= N_NODES) gr = N_NODES - 1;
        float4 v = *(const float4*)(agg + (size_t)gr * HID + c4 * 4);
        *(float4*)(xs + r * 68 + c4 * 4) = v;
    }
    __syncthreads();

    float acc[N_CLASS];
    #pragma unroll
    for (int c = 0; c < N_CLASS; ++c) acc[c] = b2[c];
    const float* xrow = xs + lane * 68;
    #pragma unroll 2
    for (int k4 = 0; k4 < 16; ++k4) {
        float4 xv = *(const float4*)(xrow + 4 * k4);
        int kb = 4 * k4 * N_CLASS;
        #pragma unroll
        for (int c = 0; c < N_CLASS; ++c) {
            acc[c] = fmaf(xv.x, W2[kb + c],               acc[c]);
            acc[c] = fmaf(xv.y, W2[kb + N_CLASS + c],     acc[c]);
            acc[c] = fmaf(xv.z, W2[kb + 2 * N_CLASS + c], acc[c]);
            acc[c] = fmaf(xv.w, W2[kb + 3 * N_CLASS + c], acc[c]);
        }
    }
    float m = acc[0];
    #pragma unroll
    for (int c = 1; c < N_CLASS; ++c) m = fmaxf(m, acc[c]);
    float ssum = 0.f;
    #pragma unroll
    for (int c = 0; c < N_CLASS; ++c) ssum += __expf(acc[c] - m);
    float lse = m + logf(ssum);

    __syncthreads();
    #pragma unroll
    for (int c4 = 0; c4 < 10; ++c4) {
        float4 o;
        o.x = acc[4 * c4 + 0] - lse; o.y = acc[4 * c4 + 1] - lse;
        o.z = acc[4 * c4 + 2] - lse; o.w = acc[4 * c4 + 3] - lse;
        *(float4*)(xs + lane * N_CLASS + c4 * 4) = o;
    }
    __syncthreads();
    #pragma unroll
    for (int j = 0; j < 10; ++j) {
        int idx = j * 64 + lane;
        if (idx < rem * 10) {
            float4 v = *(const float4*)(xs + idx * 4);
            *(float4*)(out + (size_t)base * N_CLASS + idx * 4) = v;
        }
    }
}

// ---------------------------------------------------------------------------
extern "C" void kernel_launch(void* const* d_in, const int* in_sizes, int n_in,
                              void* d_out, int out_size, void* d_ws, size_t ws_size,
                              hipStream_t stream) {
    const float* x     = (const float*)d_in[0];
    const int*   ei    = (const int*)  d_in[1];
    const float* W1    = (const float*)d_in[2];
    const float* b1    = (const float*)d_in[3];
    const float* Wc0   = (const float*)d_in[4];
    const float* as0   = (const float*)d_in[5];
    const float* ad0   = (const float*)d_in[6];
    const float* bias0 = (const float*)d_in[7];
    const float* Wc1   = (const float*)d_in[8];
    const float* as1   = (const float*)d_in[9];
    const float* ad1   = (const float*)d_in[10];
    const float* bias1 = (const float*)d_in[11];
    const float* W2    = (const float*)d_in[12];
    const float* b2    = (const float*)d_in[13];
    float* out = (float*)d_out;

    // Workspace layout (~59 MB). Staging buffers OVERLAY the node buffers:
    //   buf1 (16.5 MB) on buf_g  — buf_g first written by gemm_att (after part2)
    //   buf2 (16.4 MB) on buf_h  — buf_h first written by lin1    (after part3)
    float* buf_h  = (float*)d_ws;                      // N*64 f
    float* buf_g  = buf_h + (size_t)N_NODES * HID;     // N*64 f
    float* as_    = buf_g + (size_t)N_NODES * HID;     // N f
    float* ad_    = as_ + N_NODES;                     // N f
    int*   rowptr = (int*)(ad_ + N_NODES);             // N+1 i
    int*   col    = rowptr + (N_NODES + 1);            // ET i
    int*   tail1  = col + ET;                          // 7 i
    int*   fcnt   = tail1 + NCB;                       // 782 i (zeroed w/ tail1)
    int*   fbase  = fcnt + NFB;                        // 782 i
    int2*  buf1   = (int2*)buf_g;
    int2*  buf2   = (int2*)buf_h;

    const int AGG_BLOCKS = (N_NODES + 3) / 4;

    // ---- CSR build via 2-level LDS-staged partition (once; reused twice) ----
    hipMemsetAsync(tail1, 0, (NCB + NFB) * sizeof(int), stream);
    k_part1<<<NT1, 256, 0, stream>>>(ei, tail1, buf1);
    k_part2<<<NCB * BPC, 256, 0, stream>>>(buf1, tail1, fcnt, buf2);
    k_fscan<<<1, 1024, 0, stream>>>(fcnt, fbase, rowptr);
    k_part3<<<NFB, 256, 0, stream>>>(buf2, fcnt, fbase, rowptr, col);

    // h0 = relu(x@W1+b1) -> buf_h  (buf2 staging is dead past this point)
    k_lin1<<<ROW_BLOCKS, 64, 0, stream>>>(x, W1, b1, buf_h);

    // ---- GAT layer 0 ----  (bias0 + relu fused into aggregate epilogue)
    k_gemm_att<<<ROW_BLOCKS, 64, 0, stream>>>(buf_h, Wc0, as0, ad0,
                                              buf_g, as_, ad_);
    k_gat_agg<true><<<AGG_BLOCKS, 256, 0, stream>>>(rowptr, col, buf_g,
                                                    as_, ad_, bias0, buf_h);

    // ---- GAT layer 1 ----  (bias1 fused, no relu)
    k_gemm_att<<<ROW_BLOCKS, 64, 0, stream>>>(buf_h, Wc1, as1, ad1,
                                              buf_g, as_, ad_);
    k_gat_agg<false><<<AGG_BLOCKS, 256, 0, stream>>>(rowptr, col, buf_g,
                                                     as_, ad_, bias1, buf_h);

    // logits + log_softmax
    k_final<<<ROW_BLOCKS, 64, 0, stream>>>(buf_h, W2, b2, out);
}